// Round 11
// baseline (250.170 us; speedup 1.0000x reference)
//
#include <hip/hip_runtime.h>
#include <hip/hip_bf16.h>

#define B_  16
#define LQ  2048
#define LS  2048
#define DD  512
#define BQ  128           // block q-extent
#define BSC 128           // block s-chunk per stage
#define HK  32            // half-K granularity of the prefetch ring
#define NKC (DD / 64)     // 8 K=64 stages per s-chunk
#define NSPLIT 4

typedef short bf16x8 __attribute__((ext_vector_type(8)));
typedef float f32x4  __attribute__((ext_vector_type(4)));

// async global->LDS, 16B per lane. LDS dest = wave-uniform base + lane*16.
__device__ __forceinline__ void load_lds16(const void* g, void* l) {
  __builtin_amdgcn_global_load_lds((const __attribute__((address_space(1))) void*)g,
                                   (__attribute__((address_space(3))) void*)l,
                                   16, 0, 0);
}

__device__ __forceinline__ unsigned short f2bf(float f) {
  union { float f; unsigned int u; } v; v.f = f;
  unsigned int r = v.u + 0x7fffu + ((v.u >> 16) & 1u);  // RNE
  return (unsigned short)(r >> 16);
}

// Grid-stride cvt: 2048 blocks (first half Q, second half S).
__global__ __launch_bounds__(256) void cvt_kernel(const float* __restrict__ Q,
                                                  const float* __restrict__ S,
                                                  unsigned short* __restrict__ Qw,
                                                  unsigned short* __restrict__ Sw) {
  const int half = gridDim.x >> 1;
  int blk = blockIdx.x;
  const float* src; unsigned short* dst;
  if (blk < half) { src = Q; dst = Qw; } else { src = S; dst = Sw; blk -= half; }
  const size_t n4 = (size_t)B_ * LQ * DD / 4;
  const size_t stride = (size_t)half * 256;
  for (size_t i = (size_t)blk * 256 + threadIdx.x; i < n4; i += stride) {
    float4 f = ((const float4*)src)[i];
    ushort4 u;
    u.x = f2bf(f.x); u.y = f2bf(f.y); u.z = f2bf(f.z); u.w = f2bf(f.w);
    ((ushort4*)dst)[i] = u;
  }
}

// score[b,q] = sum_s softmax(l)[s]*l[s],  l[s] = Q[b,q,:].S[b,s,:]
// MFMA 16x16x32: A = S-tile (M=s), B = Q-tile^T (N=q) -> C[row=s][col=q]
// C layout: col = lane&15, row = (lane>>4)*4 + reg  [m89/m91]
//
// Round-11: occupancy was the binding constraint, not schedule. R10 counters:
// 116 VGPR + 128 acc ~= 244 regs/wave -> 2 waves/SIMD cap; per-SIMD wall
// 3056 cy/half vs 1241 cy MFMA demand -- two waves can't fill the per-wave
// serial chain (barrier + lgkm + issue). Every schedule variant (R2..R10)
// hit the same ~35% MfmaUtil because of this cap.
// Fix: per-wave tile 128x64 -> 64x64 (acc[4][4] = 64 regs, total ~150),
// __launch_bounds__(256,3): 3 waves/SIMD. Block = 128q x 128s-chunk, 4
// waves, 3-slot ring = 48 KiB -> 3 blocks/CU (144 KiB). 12 waves/CU from
// 3 INDEPENDENT barrier domains -> stalls of one block covered by others.
// Kept: counted-vmcnt depth-2 ring (4 loads/half, vmcnt(4) steady, never 0
// in-loop), 0-conflict (row>>1)&3 LDS swizzle (R9), L2-locality lid decode
// (FETCH 33 MB), bijective XCD chunk swizzle, grid-stride cvt.
__global__ __launch_bounds__(256, 3) void attn_kernel(const unsigned short* __restrict__ Qw,
                                                      const unsigned short* __restrict__ Sw,
                                                      float* __restrict__ out,
                                                      float* __restrict__ pm,
                                                      float* __restrict__ pse,
                                                      float* __restrict__ psel,
                                                      int nsplit) {
  // ring of 3 half-K slots: Q 128x32x2B = 8 KiB, S 128x32x2B = 8 KiB
  __shared__ __align__(16) unsigned short sQh[3][BQ * HK];   // 24 KiB
  __shared__ __align__(16) unsigned short sSh[3][BSC * HK];  // 24 KiB

  // --- chunked XCD swizzle (bijective: nwg = 256*nsplit divisible by 8) ---
  const int pid = blockIdx.x + (blockIdx.y << 4) + (blockIdx.z << 8);
  const int nch = (nsplit << 8) >> 3;          // nwg / 8
  const int lid = (pid & 7) * nch + (pid >> 3);
  // locality decode: qb fastest, then spl, then b. Concurrent set per XCD =
  // one b's Q (2 MB) + its S (2 MB) = 4 MB = L2-resident.
  const int qb   = lid & 15;                   // gridDim.x == 16
  const int rest = lid >> 4;
  const int spl  = rest & (nsplit - 1);        // nsplit in {1,4}
  const int b    = rest >> (nsplit == 4 ? 2 : 0);

  const int tid  = threadIdx.x;
  const int w    = tid >> 6;      // 0..3
  const int lane = tid & 63;
  const int h    = w & 1;         // s-half of chunk: rows [h*64, h*64+64)
  const int g    = w >> 1;        // q-half: cols [g*64, g*64+64)
  const int col  = lane & 15;
  const int quad = lane >> 4;

  const int q0 = qb * BQ;
  const unsigned short* Qb = Qw + (size_t)b * LQ * DD;
  const unsigned short* Sb = Sw + (size_t)b * LS * DD;

  float mst[4] = { -INFINITY, -INFINITY, -INFINITY, -INFINITY };
  float se[4]  = { 0.f, 0.f, 0.f, 0.f };
  float sel[4] = { 0.f, 0.f, 0.f, 0.f };

  f32x4 acc[4][4];   // [s-tile][q-tile] = 64 regs
#pragma unroll
  for (int st = 0; st < 4; ++st)
#pragma unroll
    for (int qt = 0; qt < 4; ++qt)
      acc[st][qt] = (f32x4){0.f, 0.f, 0.f, 0.f};

  // staging: lane l -> row (l>>2), slot (l&3); slot j of row r holds global
  // chunk j ^ ((r>>1)&3) -> source chunk = (l&3) ^ ((l>>3)&3)  [R9: 0 conf]
  const int cc8 = (((lane & 3) ^ ((lane >> 3) & 3)) * 8);
  const int rl  = lane >> 2;                 // row-within-16 for staging
  // read-side slot XOR: s(row) = (row>>1)&3 = (col>>1)&3 (bases %16 == 0)
  const int koq = ((quad ^ ((col >> 1) & 3)) * 8);

  // split covers LS/nsplit rows = (16/nsplit) chunks of 128
  const int ch0 = spl * (16 / nsplit);
  const int U   = (16 / nsplit) * NKC * 2;   // halves (K=32): 64 for nsplit=4

  // every wave stages Q rows [w*32,+32) (2 loads) and S rows [w*32,+32)
  // (2 loads): 4 gl_lds/wave/half, 1 KiB linear each.
  auto issue_half = [&](int u, int slot) {
    const int t  = u >> 1;                       // K=64 stage index
    const int k0 = (t & 7) * 64 + (u & 1) * 32;
    const int s0 = (ch0 + (t >> 3)) * BSC;
    const unsigned short* gq = Qb + (size_t)(q0 + w * 32 + rl) * DD + k0 + cc8;
    unsigned short* lq = &sQh[slot][(w * 32) * HK];
#pragma unroll
    for (int i = 0; i < 2; ++i)
      load_lds16(gq + (size_t)i * 16 * DD, lq + i * 16 * HK);
    const unsigned short* gs = Sb + (size_t)(s0 + w * 32 + rl) * DD + k0 + cc8;
    unsigned short* ls = &sSh[slot][(w * 32) * HK];
#pragma unroll
    for (int i = 0; i < 2; ++i)
      load_lds16(gs + (size_t)i * 16 * DD, ls + i * 16 * HK);
  };

  // prologue: fill ring depth 2
  issue_half(0, 0);
  issue_half(1, 1);
  int cs = 0;  // slot of current half u

#pragma unroll 1
  for (int u = 0; u < U; ++u) {
    // own 4 loads of half u retired; u+1's 4 keep flying (depth 2)
    if (u + 1 < U) asm volatile("s_waitcnt vmcnt(4)" ::: "memory");
    else           asm volatile("s_waitcnt vmcnt(0)" ::: "memory");
    __builtin_amdgcn_s_barrier();             // half u visible CU-wide
    {  // prefetch half u+2 into freed slot (its readers retired pre-barrier)
      int is = cs + 2; if (is >= 3) is -= 3;
      if (u + 2 < U) issue_half(u + 2, is);
    }

    const unsigned short* bq = &sQh[cs][0];
    const unsigned short* bs = &sSh[cs][0];

    bf16x8 aq[4], as[4];
#pragma unroll
    for (int qt = 0; qt < 4; ++qt)
      aq[qt] = *(const bf16x8*)&bq[(g * 64 + qt * 16 + col) * HK + koq];
#pragma unroll
    for (int st = 0; st < 4; ++st)
      as[st] = *(const bf16x8*)&bs[(h * 64 + st * 16 + col) * HK + koq];
    asm volatile("s_waitcnt lgkmcnt(0)" ::: "memory");
    __builtin_amdgcn_sched_barrier(0);
    __builtin_amdgcn_s_setprio(1);
#pragma unroll
    for (int qt = 0; qt < 4; ++qt)
#pragma unroll
      for (int st = 0; st < 4; ++st)
        acc[st][qt] = __builtin_amdgcn_mfma_f32_16x16x32_bf16(as[st], aq[qt], acc[st][qt], 0, 0, 0);
    __builtin_amdgcn_s_setprio(0);

    if ((u & (2 * NKC - 1)) == 2 * NKC - 1) {
      // online softmax-weighted-mean over this wave's 64-s rows; next
      // chunk's halves already in flight (no barrier until pair top)
#pragma unroll
      for (int qt = 0; qt < 4; ++qt) {
        float lmax = mst[qt];
#pragma unroll
        for (int st = 0; st < 4; ++st)
#pragma unroll
          for (int r = 0; r < 4; ++r)
            lmax = fmaxf(lmax, acc[st][qt][r]);
        lmax = fmaxf(lmax, __shfl_xor(lmax, 16, 64));
        lmax = fmaxf(lmax, __shfl_xor(lmax, 32, 64));
        float alpha = __expf(mst[qt] - lmax);  // exp(-inf)=0 on first block
        float pe = 0.f, pel = 0.f;
#pragma unroll
        for (int st = 0; st < 4; ++st)
#pragma unroll
          for (int r = 0; r < 4; ++r) {
            float l = acc[st][qt][r];
            float e = __expf(l - lmax);
            pe += e;
            pel = fmaf(e, l, pel);
          }
        pe  += __shfl_xor(pe, 16, 64);  pe  += __shfl_xor(pe, 32, 64);
        pel += __shfl_xor(pel, 16, 64); pel += __shfl_xor(pel, 32, 64);
        se[qt]  = fmaf(se[qt],  alpha, pe);
        sel[qt] = fmaf(sel[qt], alpha, pel);
        mst[qt] = lmax;
#pragma unroll
        for (int st = 0; st < 4; ++st)
          acc[st][qt] = (f32x4){0.f, 0.f, 0.f, 0.f};
      }
    }
    cs = (cs + 1 == 3) ? 0 : cs + 1;
  }

  // merge the two s-halves (h=0,1) per q-column via LDS, then write
  __syncthreads();
  float* red = (float*)&sQh[0][0];   // 3 KiB, ring no longer needed
  if (quad == 0) {
#pragma unroll
    for (int qt = 0; qt < 4; ++qt) {
      int qq = g * 64 + qt * 16 + col;           // 0..127
      red[h * 128 + qq]       = mst[qt];
      red[256 + h * 128 + qq] = se[qt];
      red[512 + h * 128 + qq] = sel[qt];
    }
  }
  __syncthreads();
  if (h == 0 && quad == 0) {
#pragma unroll
    for (int qt = 0; qt < 4; ++qt) {
      int qq = g * 64 + qt * 16 + col;
      float m0 = red[qq],       m1 = red[128 + qq];
      float M  = fmaxf(m0, m1);
      float a0 = __expf(m0 - M), a1 = __expf(m1 - M);
      float SE  = red[256 + qq] * a0 + red[256 + 128 + qq] * a1;
      float SEL = red[512 + qq] * a0 + red[512 + 128 + qq] * a1;
      size_t qi = (size_t)b * LQ + q0 + qq;
      if (nsplit == 1) {
        out[qi] = SEL / SE;
      } else {
        pm[qi * NSPLIT + spl]   = M;
        pse[qi * NSPLIT + spl]  = SE;
        psel[qi * NSPLIT + spl] = SEL;
      }
    }
  }
}

__global__ __launch_bounds__(256) void combine_kernel(const float* __restrict__ pm,
                                                      const float* __restrict__ pse,
                                                      const float* __restrict__ psel,
                                                      float* __restrict__ out) {
  int i = blockIdx.x * blockDim.x + threadIdx.x;
  if (i >= B_ * LQ) return;
  float M = -INFINITY;
#pragma unroll
  for (int s = 0; s < NSPLIT; ++s) M = fmaxf(M, pm[i * NSPLIT + s]);
  float SE = 0.f, SEL = 0.f;
#pragma unroll
  for (int s = 0; s < NSPLIT; ++s) {
    float a = __expf(pm[i * NSPLIT + s] - M);
    SE  = fmaf(pse[i * NSPLIT + s],  a, SE);
    SEL = fmaf(psel[i * NSPLIT + s], a, SEL);
  }
  out[i] = SEL / SE;
}

// fp32 fallback (correctness insurance if ws too small)
__global__ __launch_bounds__(256) void fallback_kernel(const float* __restrict__ Q,
                                                       const float* __restrict__ S,
                                                       float* __restrict__ out) {
  __shared__ float qv[DD];
  __shared__ float red[256];
  const int b = blockIdx.y, qi = blockIdx.x, tid = threadIdx.x;
  const float* qrow = Q + ((size_t)b * LQ + qi) * DD;
  for (int d = tid; d < DD; d += 256) qv[d] = qrow[d];
  __syncthreads();
  const float* Sb = S + (size_t)b * LS * DD;
  float m = -INFINITY, se = 0.f, sel = 0.f;
  for (int s = tid; s < LS; s += 256) {
    const float* srow = Sb + (size_t)s * DD;
    float dot = 0.f;
    for (int d = 0; d < DD; ++d) dot = fmaf(qv[d], srow[d], dot);
    float mn = fmaxf(m, dot);
    float a = __expf(m - mn);
    float e = __expf(dot - mn);
    se  = se * a + e;
    sel = sel * a + e * dot;
    m = mn;
  }
  red[tid] = m; __syncthreads();
  for (int o = 128; o > 0; o >>= 1) { if (tid < o) red[tid] = fmaxf(red[tid], red[tid + o]); __syncthreads(); }
  float M = red[0]; __syncthreads();
  float a = __expf(m - M); se *= a; sel *= a;
  red[tid] = se; __syncthreads();
  for (int o = 128; o > 0; o >>= 1) { if (tid < o) red[tid] += red[tid + o]; __syncthreads(); }
  float SE = red[0]; __syncthreads();
  red[tid] = sel; __syncthreads();
  for (int o = 128; o > 0; o >>= 1) { if (tid < o) red[tid] += red[tid + o]; __syncthreads(); }
  float SEL = red[0];
  if (tid == 0) out[(size_t)b * LQ + qi] = SEL / SE;
}

extern "C" void kernel_launch(void* const* d_in, const int* in_sizes, int n_in,
                              void* d_out, int out_size, void* d_ws, size_t ws_size,
                              hipStream_t stream) {
  const float* Q = (const float*)d_in[0];
  const float* S = (const float*)d_in[1];
  float* out = (float*)d_out;
  const size_t nelem = (size_t)B_ * LQ * DD;                    // 16.78M / tensor
  const size_t need_base  = 2 * nelem * sizeof(unsigned short); // 67 MiB
  const size_t part_elems = (size_t)B_ * LQ * NSPLIT;
  const size_t need_split = need_base + 3 * part_elems * sizeof(float);

  if (ws_size >= need_base) {
    unsigned short* Qw = (unsigned short*)d_ws;
    unsigned short* Sw = Qw + nelem;
    cvt_kernel<<<2048, 256, 0, stream>>>(Q, S, Qw, Sw);
    if (ws_size >= need_split) {
      float* pm   = (float*)(Sw + nelem);
      float* pse  = pm + part_elems;
      float* psel = pse + part_elems;
      attn_kernel<<<dim3(LQ / BQ, B_, NSPLIT), 256, 0, stream>>>(Qw, Sw, out, pm, pse, psel, NSPLIT);
      combine_kernel<<<(B_ * LQ + 255) / 256, 256, 0, stream>>>(pm, pse, psel, out);
    } else {
      attn_kernel<<<dim3(LQ / BQ, B_, 1), 256, 0, stream>>>(Qw, Sw, out, nullptr, nullptr, nullptr, 1);
    }
  } else {
    fallback_kernel<<<dim3(LQ, B_), 256, 0, stream>>>(Q, S, out);
  }
}